// Round 4
// baseline (97.987 us; speedup 1.0000x reference)
//
#include <hip/hip_runtime.h>

#define Bn   4
#define Nn   1024
#define Mn   100
#define NB   25
#define FEAT 50
#define Hn   100
#define PIc  3.1415926f
#define RMAXc 6.0f
#define RSTEP (5.5f / 24.0f)

#define ATB  16                         // atoms per MLP block
#define GA   4                          // atoms per 128-thread group
#define WS   101                        // LDS weight stride (odd => conflict-free both scans)
#define NATOMS (Bn * Nn)
#define ORDER_LEN (NATOMS + ATB)        // 4112
#define MLP_BLOCKS (ORDER_LEN / ATB)    // 257

#define GPB  32       // force blocks per batch
#define CPG  32       // centers per force block
#define FTHREADS 512

__device__ __forceinline__ float fast_tanh(float x) {
    float ax = fabsf(x);
    float t  = __expf(-2.0f * ax);
    float r  = (1.0f - t) * __builtin_amdgcn_rcpf(1.0f + t);
    return copysignf(r, x);
}

// ---------------------------------------------------------------- sort ----
__global__ __launch_bounds__(1024) void sort_kernel(
    const int* __restrict__ itype, int* __restrict__ order)
{
    const int t = threadIdx.x;
    __shared__ int scan[1024];

    for (int i = t; i < ORDER_LEN; i += 1024) order[i] = -1;

    int ty[4]; int c0 = 0;
    #pragma unroll
    for (int k = 0; k < 4; ++k) {
        int ty_ = (itype[t * 4 + k] == 8) ? 1 : 0;
        ty[k] = ty_; c0 += 1 - ty_;
    }
    scan[t] = c0;
    __syncthreads();
    for (int off = 1; off < 1024; off <<= 1) {
        int v = scan[t];
        int add = (t >= off) ? scan[t - off] : 0;
        __syncthreads();
        scan[t] = v + add;
        __syncthreads();
    }
    const int total0 = scan[1023];
    const int ex0 = scan[t] - c0;
    const int ex1 = 4 * t - ex0;
    const int pad0 = (total0 + (ATB - 1)) & ~(ATB - 1);
    int p0 = ex0, p1 = pad0 + ex1;
    #pragma unroll
    for (int k = 0; k < 4; ++k) {
        int idx = t * 4 + k;
        if (ty[k] == 0) order[p0++] = idx; else order[p1++] = idx;
    }
}

// ---------------------------------------------------------------- feat ----
__global__ __launch_bounds__(128) void feat_kernel(
    const int* __restrict__ itype, const int* __restrict__ nlist,
    const float* __restrict__ dR, float* __restrict__ feat)
{
    const int atom = blockIdx.x;
    const int b = atom >> 10;
    const int t = threadIdx.x;

    __shared__ float rsh[Mn];
    __shared__ float csh[Mn];
    __shared__ int   tsh[Mn];

    if (t < Mn) {
        float r = dR[((size_t)atom * Mn + t) * 4 + 0];
        int v = nlist[(size_t)atom * Mn + t];
        int tt = -1;
        if (v > 0) tt = (itype[b * Nn + (v - 1)] == 8) ? 1 : 0;
        if (!(r < RMAXc && r > 0.0f)) tt = -1;
        rsh[t] = r;
        csh[t] = 0.5f * __cosf(PIc * r) + 0.5f;
        tsh[t] = tt;
    }
    __syncthreads();

    if (t < FEAT) {
        const int tt = t / NB;
        const int k  = t - tt * NB;
        const float rk = 0.5f + k * RSTEP;
        float acc = 0.0f;
        for (int m = 0; m < Mn; ++m) {
            if (tsh[m] == tt) {
                float d = rsh[m] - rk;
                acc += __expf(-d * d) * csh[m];
            }
        }
        feat[(size_t)atom * FEAT + t] = acc;
    }
}

// ----------------------------------------------------------------- mlp ----
// 512 threads = 4 groups x 128. Group g handles atoms a0..a0+3 (type-pure via
// order[]). Weight layers staged into one LDS buffer (stride 101: odd stride
// => conflict-free column scan (fwd) AND row scan (bwd)). 5 stagings total:
// w0,w1,w2 fwd; w2 reused for bwd; w1,w0 restaged.
__device__ __forceinline__ void stage_w(const float* __restrict__ gsrc,
                                        float* __restrict__ wsh,
                                        int rows, int t)
{
    const int nq = rows * 25;                 // float4 count (row width 100)
    const float4* g4 = (const float4*)gsrc;
    for (int q = t; q < nq; q += 512) {
        float4 v = g4[q];
        int i = q / 25;
        int jj = (q - i * 25) << 2;
        float* d = &wsh[i * WS + jj];
        d[0] = v.x; d[1] = v.y; d[2] = v.z; d[3] = v.w;
    }
}

__global__ __launch_bounds__(512) void mlp_kernel(
    const float* __restrict__ feat, const int* __restrict__ itype,
    const int* __restrict__ order,
    const float* __restrict__ W0, const float* __restrict__ B0,
    const float* __restrict__ W1, const float* __restrict__ B1,
    const float* __restrict__ W2, const float* __restrict__ B2,
    const float* __restrict__ W3, const float* __restrict__ B3,
    float* __restrict__ Ei, float* __restrict__ dE)
{
    const int t = threadIdx.x;
    const int g = t >> 7;
    const int j = t & 127;
    const int base = blockIdx.x * ATB;

    __shared__ float wsh[100 * WS];      // 40.4 KB
    __shared__ float w3sh[128];
    __shared__ float fsh[ATB][FEAT];
    __shared__ float xs[ATB][Hn];
    __shared__ float dzs[ATB][Hn];
    __shared__ float dx1s[ATB][Hn];
    __shared__ int   aidsh[ATB];
    __shared__ float redsh[ATB][2];

    if (t < ATB) aidsh[t] = order[base + t];
    __syncthreads();

    int first = -1;
    #pragma unroll
    for (int a = 0; a < ATB; ++a) {
        int v = aidsh[a];
        if (first < 0 && v >= 0) first = v;
    }
    if (first < 0) return;               // uniform over block
    const int tnet = (itype[first] == 8) ? 1 : 0;

    // stage feats + w0 + w3
    for (int idx = t; idx < ATB * FEAT; idx += 512) {
        int a = idx / FEAT, f = idx - a * FEAT;
        int v = aidsh[a];
        fsh[a][f] = (v >= 0) ? feat[(size_t)v * FEAT + f] : 0.0f;
    }
    stage_w(W0 + (size_t)tnet * FEAT * Hn, wsh, FEAT, t);
    if (t < 128) w3sh[t] = (t < Hn) ? W3[tnet * Hn + t] : 0.0f;
    __syncthreads();                                    // BAR0

    const int a0 = g * GA;
    float z0, z1, z2, z3;
    float h0[GA], h1[GA], h2[GA], x1[GA], x2[GA], x3[GA];

    // ---------------- L0 ----------------
    if (j < Hn) {
        float bj = B0[tnet * Hn + j];
        z0 = z1 = z2 = z3 = bj;
        #pragma unroll 5
        for (int i2 = 0; i2 < 25; ++i2) {
            float2 f0 = ((const float2*)fsh[a0 + 0])[i2];
            float2 f1 = ((const float2*)fsh[a0 + 1])[i2];
            float2 f2 = ((const float2*)fsh[a0 + 2])[i2];
            float2 f3 = ((const float2*)fsh[a0 + 3])[i2];
            const float* wr = &wsh[(i2 * 2) * WS + j];
            float wa = wr[0], wb = wr[WS];
            z0 += f0.x * wa + f0.y * wb;
            z1 += f1.x * wa + f1.y * wb;
            z2 += f2.x * wa + f2.y * wb;
            z3 += f3.x * wa + f3.y * wb;
        }
        const int jf = (j < FEAT) ? j : j - FEAT;
        h0[0] = fast_tanh(z0); x1[0] = h0[0] + fsh[a0 + 0][jf]; xs[a0 + 0][j] = x1[0];
        h0[1] = fast_tanh(z1); x1[1] = h0[1] + fsh[a0 + 1][jf]; xs[a0 + 1][j] = x1[1];
        h0[2] = fast_tanh(z2); x1[2] = h0[2] + fsh[a0 + 2][jf]; xs[a0 + 2][j] = x1[2];
        h0[3] = fast_tanh(z3); x1[3] = h0[3] + fsh[a0 + 3][jf]; xs[a0 + 3][j] = x1[3];
    }
    __syncthreads();                                    // BAR1: xs(x1) ready, w0 consumed
    stage_w(W1 + (size_t)tnet * Hn * Hn, wsh, Hn, t);
    __syncthreads();                                    // BAR2: w1 ready

    // ---------------- L1 ----------------
    if (j < Hn) {
        float bj = B1[tnet * Hn + j];
        z0 = z1 = z2 = z3 = bj;
        #pragma unroll 5
        for (int i4 = 0; i4 < 25; ++i4) {
            float4 v0 = ((const float4*)xs[a0 + 0])[i4];
            float4 v1 = ((const float4*)xs[a0 + 1])[i4];
            float4 v2 = ((const float4*)xs[a0 + 2])[i4];
            float4 v3 = ((const float4*)xs[a0 + 3])[i4];
            const float* wr = &wsh[(i4 * 4) * WS + j];
            float wa = wr[0], wb = wr[WS], wc = wr[2 * WS], wd = wr[3 * WS];
            z0 += v0.x * wa + v0.y * wb + v0.z * wc + v0.w * wd;
            z1 += v1.x * wa + v1.y * wb + v1.z * wc + v1.w * wd;
            z2 += v2.x * wa + v2.y * wb + v2.z * wc + v2.w * wd;
            z3 += v3.x * wa + v3.y * wb + v3.z * wc + v3.w * wd;
        }
        h1[0] = fast_tanh(z0); x2[0] = h1[0] + x1[0];
        h1[1] = fast_tanh(z1); x2[1] = h1[1] + x1[1];
        h1[2] = fast_tanh(z2); x2[2] = h1[2] + x1[2];
        h1[3] = fast_tanh(z3); x2[3] = h1[3] + x1[3];
    }
    __syncthreads();                                    // BAR3: xs(x1) reads done, w1 consumed
    if (j < Hn) {
        xs[a0 + 0][j] = x2[0]; xs[a0 + 1][j] = x2[1];
        xs[a0 + 2][j] = x2[2]; xs[a0 + 3][j] = x2[3];
    }
    stage_w(W2 + (size_t)tnet * Hn * Hn, wsh, Hn, t);
    __syncthreads();                                    // BAR4: xs(x2)+w2 ready

    // ---------------- L2 ----------------
    if (j < Hn) {
        float bj = B2[tnet * Hn + j];
        z0 = z1 = z2 = z3 = bj;
        #pragma unroll 5
        for (int i4 = 0; i4 < 25; ++i4) {
            float4 v0 = ((const float4*)xs[a0 + 0])[i4];
            float4 v1 = ((const float4*)xs[a0 + 1])[i4];
            float4 v2 = ((const float4*)xs[a0 + 2])[i4];
            float4 v3 = ((const float4*)xs[a0 + 3])[i4];
            const float* wr = &wsh[(i4 * 4) * WS + j];
            float wa = wr[0], wb = wr[WS], wc = wr[2 * WS], wd = wr[3 * WS];
            z0 += v0.x * wa + v0.y * wb + v0.z * wc + v0.w * wd;
            z1 += v1.x * wa + v1.y * wb + v1.z * wc + v1.w * wd;
            z2 += v2.x * wa + v2.y * wb + v2.z * wc + v2.w * wd;
            z3 += v3.x * wa + v3.y * wb + v3.z * wc + v3.w * wd;
        }
        h2[0] = fast_tanh(z0); x3[0] = h2[0] + x2[0];
        h2[1] = fast_tanh(z1); x3[1] = h2[1] + x2[1];
        h2[2] = fast_tanh(z2); x3[2] = h2[2] + x2[2];
        h2[3] = fast_tanh(z3); x3[3] = h2[3] + x2[3];
    }

    // ---- Ei: wave shuffle reduce; also write dz2 into dzs ----
    {
        const float w3j = (j < Hn) ? w3sh[j] : 0.0f;
        #pragma unroll
        for (int a = 0; a < GA; ++a) {
            float v = (j < Hn) ? x3[a] * w3j : 0.0f;
            #pragma unroll
            for (int off = 32; off > 0; off >>= 1) v += __shfl_xor(v, off);
            if ((t & 63) == 0) redsh[a0 + a][(j >> 6) & 1] = v;
        }
        if (j < Hn) {
            #pragma unroll
            for (int a = 0; a < GA; ++a)
                dzs[a0 + a][j] = w3j * (1.0f - h2[a] * h2[a]);
        }
    }
    __syncthreads();                                    // BAR5: redsh + dzs(dz2) ready
    if (t < ATB) {
        int v = aidsh[t];
        if (v >= 0) Ei[v] = redsh[t][0] + redsh[t][1] + B3[tnet];
    }

    // ---- bwd L2: dx2 = w3 + w2^T dz2 (w2 still staged) ----
    float dx2[GA];
    if (j < Hn) {
        float a0acc = w3sh[j], a1acc = w3sh[j], a2acc = w3sh[j], a3acc = w3sh[j];
        const float* wrow = &wsh[j * WS];
        #pragma unroll 5
        for (int q = 0; q < 25; ++q) {
            float4 d0 = ((const float4*)dzs[a0 + 0])[q];
            float4 d1 = ((const float4*)dzs[a0 + 1])[q];
            float4 d2 = ((const float4*)dzs[a0 + 2])[q];
            float4 d3 = ((const float4*)dzs[a0 + 3])[q];
            const float* wr = wrow + q * 4;
            float wa = wr[0], wb = wr[1], wc = wr[2], wd = wr[3];
            a0acc += wa * d0.x + wb * d0.y + wc * d0.z + wd * d0.w;
            a1acc += wa * d1.x + wb * d1.y + wc * d1.z + wd * d1.w;
            a2acc += wa * d2.x + wb * d2.y + wc * d2.z + wd * d2.w;
            a3acc += wa * d3.x + wb * d3.y + wc * d3.z + wd * d3.w;
        }
        dx2[0] = a0acc; dx2[1] = a1acc; dx2[2] = a2acc; dx2[3] = a3acc;
    }
    __syncthreads();                                    // BAR B: dzs reads done, w2 free
    if (j < Hn) {
        #pragma unroll
        for (int a = 0; a < GA; ++a)
            dzs[a0 + a][j] = dx2[a] * (1.0f - h1[a] * h1[a]);
    }
    stage_w(W1 + (size_t)tnet * Hn * Hn, wsh, Hn, t);
    __syncthreads();                                    // BAR C: dz1 + w1 ready

    float dx1[GA];
    if (j < Hn) {
        float a0acc = dx2[0], a1acc = dx2[1], a2acc = dx2[2], a3acc = dx2[3];
        const float* wrow = &wsh[j * WS];
        #pragma unroll 5
        for (int q = 0; q < 25; ++q) {
            float4 d0 = ((const float4*)dzs[a0 + 0])[q];
            float4 d1 = ((const float4*)dzs[a0 + 1])[q];
            float4 d2 = ((const float4*)dzs[a0 + 2])[q];
            float4 d3 = ((const float4*)dzs[a0 + 3])[q];
            const float* wr = wrow + q * 4;
            float wa = wr[0], wb = wr[1], wc = wr[2], wd = wr[3];
            a0acc += wa * d0.x + wb * d0.y + wc * d0.z + wd * d0.w;
            a1acc += wa * d1.x + wb * d1.y + wc * d1.z + wd * d1.w;
            a2acc += wa * d2.x + wb * d2.y + wc * d2.z + wd * d2.w;
            a3acc += wa * d3.x + wb * d3.y + wc * d3.z + wd * d3.w;
        }
        dx1[0] = a0acc; dx1[1] = a1acc; dx1[2] = a2acc; dx1[3] = a3acc;
        dx1s[a0 + 0][j] = dx1[0]; dx1s[a0 + 1][j] = dx1[1];
        dx1s[a0 + 2][j] = dx1[2]; dx1s[a0 + 3][j] = dx1[3];
    }
    __syncthreads();                                    // BAR D: dzs(dz1) reads + dx1s done
    if (j < Hn) {
        #pragma unroll
        for (int a = 0; a < GA; ++a)
            dzs[a0 + a][j] = dx1[a] * (1.0f - h0[a] * h0[a]);
    }
    stage_w(W0 + (size_t)tnet * FEAT * Hn, wsh, FEAT, t);
    __syncthreads();                                    // BAR E: dz0 + w0 ready

    if (j < FEAT) {
        float a0acc = dx1s[a0 + 0][j] + dx1s[a0 + 0][j + FEAT];
        float a1acc = dx1s[a0 + 1][j] + dx1s[a0 + 1][j + FEAT];
        float a2acc = dx1s[a0 + 2][j] + dx1s[a0 + 2][j + FEAT];
        float a3acc = dx1s[a0 + 3][j] + dx1s[a0 + 3][j + FEAT];
        const float* wrow = &wsh[j * WS];
        #pragma unroll 5
        for (int q = 0; q < 25; ++q) {
            float4 d0 = ((const float4*)dzs[a0 + 0])[q];
            float4 d1 = ((const float4*)dzs[a0 + 1])[q];
            float4 d2 = ((const float4*)dzs[a0 + 2])[q];
            float4 d3 = ((const float4*)dzs[a0 + 3])[q];
            const float* wr = wrow + q * 4;
            float wa = wr[0], wb = wr[1], wc = wr[2], wd = wr[3];
            a0acc += wa * d0.x + wb * d0.y + wc * d0.z + wd * d0.w;
            a1acc += wa * d1.x + wb * d1.y + wc * d1.z + wd * d1.w;
            a2acc += wa * d2.x + wb * d2.y + wc * d2.z + wd * d2.w;
            a3acc += wa * d3.x + wb * d3.y + wc * d3.z + wd * d3.w;
        }
        int v0 = aidsh[a0 + 0], v1 = aidsh[a0 + 1];
        int v2 = aidsh[a0 + 2], v3 = aidsh[a0 + 3];
        if (v0 >= 0) dE[(size_t)v0 * FEAT + j] = a0acc;
        if (v1 >= 0) dE[(size_t)v1 * FEAT + j] = a1acc;
        if (v2 >= 0) dE[(size_t)v2 * FEAT + j] = a2acc;
        if (v3 >= 0) dE[(size_t)v3 * FEAT + j] = a3acc;
    }
}

// ---------------------------------------------------------------- etot ----
__global__ __launch_bounds__(256) void etot_kernel(
    const float* __restrict__ Ei, float* __restrict__ Etot)
{
    const int b = blockIdx.x, t = threadIdx.x;
    __shared__ float red[256];
    float s = 0.0f;
    for (int i = t; i < Nn; i += 256) s += Ei[b * Nn + i];
    red[t] = s;
    __syncthreads();
    for (int st = 128; st > 0; st >>= 1) {
        if (t < st) red[t] += red[t + st];
        __syncthreads();
    }
    if (t == 0) Etot[b] = red[0];
}

// --------------------------------------------------------------- force ----
__global__ __launch_bounds__(FTHREADS) void force_kernel(
    const int* __restrict__ itype, const int* __restrict__ nlist,
    const float* __restrict__ dR, const float* __restrict__ dE,
    float* __restrict__ partial)
{
    const int blk = blockIdx.x;
    const int b = blk / GPB;
    const int g = blk - b * GPB;
    const int t = threadIdx.x;

    __shared__ float acc[(Nn + 1) * 3];
    __shared__ float desh[CPG][FEAT];

    for (int idx = t; idx < (Nn + 1) * 3; idx += FTHREADS) acc[idx] = 0.0f;
    for (int idx = t; idx < CPG * FEAT; idx += FTHREADS)
        ((float*)desh)[idx] = dE[((size_t)(b * Nn) + g * CPG) * FEAT + idx];
    __syncthreads();

    for (int p = t; p < CPG * Mn; p += FTHREADS) {
        int c = p / Mn, m = p - c * Mn;
        int n = g * CPG + c;
        size_t pair = (size_t)(b * Nn + n) * Mn + m;
        float4 q = ((const float4*)dR)[pair];
        int v = nlist[pair];
        if (v > 0) {
            float r = q.x;
            if (r < RMAXc && r > 0.0f) {
                int tt = (itype[b * Nn + v - 1] == 8) ? 1 : 0;
                float cw  = 0.5f * __cosf(PIc * r) + 0.5f;
                float dcw = -0.5f * PIc * __sinf(PIc * r);
                float s = 0.0f;
                const float* de = &desh[c][tt * NB];
                #pragma unroll
                for (int k = 0; k < NB; ++k) {
                    float d = r - (0.5f + k * RSTEP);
                    float e = __expf(-d * d);
                    s += de[k] * (e * dcw - 2.0f * d * e * cw);
                }
                float inv = 1.0f / r;
                float fx = s * q.y * inv, fy = s * q.z * inv, fz = s * q.w * inv;
                atomicAdd(&acc[v * 3 + 0], fx);
                atomicAdd(&acc[v * 3 + 1], fy);
                atomicAdd(&acc[v * 3 + 2], fz);
                atomicAdd(&acc[(n + 1) * 3 + 0], -fx);
                atomicAdd(&acc[(n + 1) * 3 + 1], -fy);
                atomicAdd(&acc[(n + 1) * 3 + 2], -fz);
            }
        }
    }
    __syncthreads();

    float* pout = partial + (size_t)blk * ((Nn + 1) * 3);
    for (int idx = t; idx < (Nn + 1) * 3; idx += FTHREADS) pout[idx] = acc[idx];
}

// ------------------------------------------------------------- freduce ----
__global__ __launch_bounds__(256) void freduce_kernel(
    const float* __restrict__ partial, float* __restrict__ Force)
{
    int idx = blockIdx.x * 256 + threadIdx.x;
    if (idx >= Bn * Nn * 3) return;
    int b = idx / (Nn * 3);
    int r = idx - b * (Nn * 3);
    int i = r / 3, ch = r - i * 3;
    float s = 0.0f;
    for (int g = 0; g < GPB; ++g)
        s += partial[((size_t)(b * GPB + g)) * ((Nn + 1) * 3) + (size_t)(i + 1) * 3 + ch];
    Force[idx] = s;
}

// -------------------------------------------------------------- launch ----
extern "C" void kernel_launch(void* const* d_in, const int* in_sizes, int n_in,
                              void* d_out, int out_size, void* d_ws, size_t ws_size,
                              hipStream_t stream)
{
    const int*   itype = (const int*)d_in[0];
    const int*   nlist = (const int*)d_in[1];
    const float* dR    = (const float*)d_in[2];
    const float* W0 = (const float*)d_in[3];  const float* B0 = (const float*)d_in[4];
    const float* W1 = (const float*)d_in[5];  const float* B1 = (const float*)d_in[6];
    const float* W2 = (const float*)d_in[7];  const float* B2 = (const float*)d_in[8];
    const float* W3 = (const float*)d_in[9];  const float* B3 = (const float*)d_in[10];

    float* out   = (float*)d_out;
    float* Etot  = out;                    // [B,1]
    float* Ei    = out + Bn;               // [B,N,1]
    float* Force = out + Bn + Bn * Nn;     // [B,N,3]

    float* feat    = (float*)d_ws;                          // 4096*50
    float* dE      = feat + (size_t)NATOMS * FEAT;          // 4096*50
    float* partial = dE + (size_t)NATOMS * FEAT;            // Bn*GPB*(Nn+1)*3
    int*   order   = (int*)(partial + (size_t)Bn * GPB * (Nn + 1) * 3);

    sort_kernel   <<<1, 1024, 0, stream>>>(itype, order);
    feat_kernel   <<<NATOMS, 128, 0, stream>>>(itype, nlist, dR, feat);
    mlp_kernel    <<<MLP_BLOCKS, 512, 0, stream>>>(feat, itype, order,
                                                   W0, B0, W1, B1, W2, B2, W3, B3,
                                                   Ei, dE);
    etot_kernel   <<<Bn, 256, 0, stream>>>(Ei, Etot);
    force_kernel  <<<Bn * GPB, FTHREADS, 0, stream>>>(itype, nlist, dR, dE, partial);
    freduce_kernel<<<(Bn * Nn * 3 + 255) / 256, 256, 0, stream>>>(partial, Force);
}

// Round 5
// 90.445 us; speedup vs baseline: 1.0834x; 1.0834x over previous
//
#include <hip/hip_runtime.h>

#define Bn   4
#define Nn   1024
#define Mn   100
#define NB   25
#define FEAT 50
#define Hn   100
#define PIc  3.1415926f
#define RMAXc 6.0f
#define RSTEP (5.5f / 24.0f)

#define ATB  16                          // atoms per MLP block
#define NATOMS (Bn * Nn)
#define ORDER_LEN (NATOMS + ATB)         // 4112
#define MLP_BLOCKS (ORDER_LEN / ATB)     // 257

#define GPB  32
#define CPG  32
#define FTHREADS 512

// ---- bf16 split-weight region offsets (ushort elements) ----
#define OFF_WT0H  0          // [2][128][64]   fwd L0: Wt[j][k]=W0[k][j]
#define OFF_WT0L  16384
#define OFF_WRM0H 32768      // [2][64][128]   bwd L0: W0[f][j]
#define OFF_WRM0L 49152
#define OFF_WT1H  65536      // [2][128][128]
#define OFF_WT1L  98304
#define OFF_WT2H  131072
#define OFF_WT2L  163840
#define OFF_WRM1H 196608
#define OFF_WRM1L 229376
#define OFF_WRM2H 262144
#define OFF_WRM2L 294912
#define WSPLIT_TOTAL 327680

typedef __attribute__((ext_vector_type(8))) short bf16x8;
typedef __attribute__((ext_vector_type(4))) float f32x4;

__device__ __forceinline__ unsigned short f2bh(float x) {
    union { float f; unsigned u; } v; v.f = x;
    unsigned r = v.u + 0x7fffu + ((v.u >> 16) & 1u);
    return (unsigned short)(r >> 16);
}
__device__ __forceinline__ float bh2f(unsigned short h) {
    union { unsigned u; float f; } v; v.u = ((unsigned)h) << 16; return v.f;
}
__device__ __forceinline__ float fast_tanh(float x) {
    float ax = fabsf(x);
    float t  = __expf(-2.0f * ax);
    float r  = (1.0f - t) * __builtin_amdgcn_rcpf(1.0f + t);
    return copysignf(r, x);
}

// ------------------------------------------------------- prep (+sort) ----
// block 0: type-partition sort (order[]); blocks 1..640: split weights to
// bf16 hi/lo in fwd ([j][k]) and bwd ([i][j]) layouts, zero-padded.
__global__ __launch_bounds__(256) void prep_kernel(
    const int* __restrict__ itype,
    const float* __restrict__ W0, const float* __restrict__ W1,
    const float* __restrict__ W2,
    int* __restrict__ order, unsigned short* __restrict__ wsu)
{
    if (blockIdx.x == 0) {
        const int t = threadIdx.x;
        __shared__ int scan[256];
        for (int i = t; i < ORDER_LEN; i += 256) order[i] = -1;
        int tyv[16]; int c0 = 0;
        #pragma unroll
        for (int k = 0; k < 16; ++k) {
            int tt = (itype[t * 16 + k] == 8) ? 1 : 0;
            tyv[k] = tt; c0 += 1 - tt;
        }
        scan[t] = c0;
        __syncthreads();
        for (int off = 1; off < 256; off <<= 1) {
            int v = scan[t];
            int add = (t >= off) ? scan[t - off] : 0;
            __syncthreads();
            scan[t] = v + add;
            __syncthreads();
        }
        int total0 = scan[255];
        int ex0 = scan[t] - c0;
        int ex1 = 16 * t - ex0;
        int pad0 = (total0 + 15) & ~15;
        int p0 = ex0, p1 = pad0 + ex1;
        #pragma unroll
        for (int k = 0; k < 16; ++k) {
            int idx = t * 16 + k;
            if (tyv[k] == 0) order[p0++] = idx; else order[p1++] = idx;
        }
        return;
    }

    int idx = (blockIdx.x - 1) * 256 + threadIdx.x;   // < 163840
    int ty = idx / 81920;
    int r  = idx - ty * 81920;
    float v = 0.0f;
    int dh, dl;
    if (r < 8192) {                       // WT0 [128 j][64 k]
        int j = r >> 6, k = r & 63;
        if (j < 100 && k < 50) v = W0[ty * 5000 + k * 100 + j];
        dh = OFF_WT0H + ty * 8192 + r;  dl = OFF_WT0L + ty * 8192 + r;
    } else if (r < 16384) {               // WRM0 [64 f][128 j]
        int r2 = r - 8192; int f = r2 >> 7, j = r2 & 127;
        if (f < 50 && j < 100) v = W0[ty * 5000 + f * 100 + j];
        dh = OFF_WRM0H + ty * 8192 + r2; dl = OFF_WRM0L + ty * 8192 + r2;
    } else if (r < 32768) {               // WT1 [128 j][128 k]
        int r2 = r - 16384; int j = r2 >> 7, k = r2 & 127;
        if (j < 100 && k < 100) v = W1[ty * 10000 + k * 100 + j];
        dh = OFF_WT1H + ty * 16384 + r2; dl = OFF_WT1L + ty * 16384 + r2;
    } else if (r < 49152) {               // WT2
        int r2 = r - 32768; int j = r2 >> 7, k = r2 & 127;
        if (j < 100 && k < 100) v = W2[ty * 10000 + k * 100 + j];
        dh = OFF_WT2H + ty * 16384 + r2; dl = OFF_WT2L + ty * 16384 + r2;
    } else if (r < 65536) {               // WRM1 [128 i][128 j]
        int r2 = r - 49152; int i = r2 >> 7, j = r2 & 127;
        if (i < 100 && j < 100) v = W1[ty * 10000 + i * 100 + j];
        dh = OFF_WRM1H + ty * 16384 + r2; dl = OFF_WRM1L + ty * 16384 + r2;
    } else {                              // WRM2
        int r2 = r - 65536; int i = r2 >> 7, j = r2 & 127;
        if (i < 100 && j < 100) v = W2[ty * 10000 + i * 100 + j];
        dh = OFF_WRM2H + ty * 16384 + r2; dl = OFF_WRM2L + ty * 16384 + r2;
    }
    unsigned short h = f2bh(v);
    wsu[dh] = h;
    wsu[dl] = f2bh(v - bh2f(h));
}

// ---------------------------------------------------------------- feat ----
__global__ __launch_bounds__(128) void feat_kernel(
    const int* __restrict__ itype, const int* __restrict__ nlist,
    const float* __restrict__ dR, float* __restrict__ feat)
{
    const int atom = blockIdx.x;
    const int b = atom >> 10;
    const int t = threadIdx.x;

    __shared__ float rsh[Mn];
    __shared__ float csh[Mn];
    __shared__ int   tsh[Mn];

    if (t < Mn) {
        float r = dR[((size_t)atom * Mn + t) * 4 + 0];
        int v = nlist[(size_t)atom * Mn + t];
        int tt = -1;
        if (v > 0) tt = (itype[b * Nn + (v - 1)] == 8) ? 1 : 0;
        if (!(r < RMAXc && r > 0.0f)) tt = -1;
        rsh[t] = r;
        csh[t] = 0.5f * __cosf(PIc * r) + 0.5f;
        tsh[t] = tt;
    }
    __syncthreads();

    if (t < FEAT) {
        const int tt = t / NB;
        const int k  = t - tt * NB;
        const float rk = 0.5f + k * RSTEP;
        float acc = 0.0f;
        for (int m = 0; m < Mn; ++m) {
            if (tsh[m] == tt) {
                float d = rsh[m] - rk;
                acc += __expf(-d * d) * csh[m];
            }
        }
        feat[(size_t)atom * FEAT + t] = acc;
    }
}

// ----------------------------------------------------------------- mlp ----
// 128 threads = 2 waves; 16 type-pure atoms. Split-bf16 MFMA GEMMs:
// each GEMM pass = 3x mfma_f32_16x16x32_bf16 per (n,k) tile (hi/lo split).
// A (activations/dz) in XOR-swizzled LDS [16][128]; B direct from L2.
#define GEMM_PASS(SRCBUF, WH, WL, NKT, RW, NTBASE, NACC, ACC)                        \
    {                                                                                \
        _Pragma("unroll")                                                            \
        for (int kt = 0; kt < NKT; ++kt) {                                           \
            int ka = kt * 32 + q * 8;                                                \
            int ap = (c << 7) | (ka ^ ((c & 7) << 3));                               \
            bf16x8 ah = *(const bf16x8*)&aAh[SRCBUF][ap];                            \
            bf16x8 al = *(const bf16x8*)&aAl[SRCBUF][ap];                            \
            _Pragma("unroll")                                                        \
            for (int n = 0; n < NACC; ++n) {                                         \
                int jj = c + 16 * ((NTBASE) + n);                                    \
                int off = jj * (RW) + kt * 32 + q * 8;                               \
                bf16x8 bh = *(const bf16x8*)((WH) + off);                            \
                bf16x8 bl = *(const bf16x8*)((WL) + off);                            \
                ACC[n] = __builtin_amdgcn_mfma_f32_16x16x32_bf16(ah, bh, ACC[n], 0, 0, 0); \
                ACC[n] = __builtin_amdgcn_mfma_f32_16x16x32_bf16(ah, bl, ACC[n], 0, 0, 0); \
                ACC[n] = __builtin_amdgcn_mfma_f32_16x16x32_bf16(al, bh, ACC[n], 0, 0, 0); \
            }                                                                        \
        }                                                                            \
    }

__global__ __launch_bounds__(128) void mlp_kernel(
    const float* __restrict__ feat, const int* __restrict__ itype,
    const int* __restrict__ order, const unsigned short* __restrict__ wsu,
    const float* __restrict__ B0, const float* __restrict__ B1,
    const float* __restrict__ B2, const float* __restrict__ W3,
    const float* __restrict__ B3,
    float* __restrict__ Ei, float* __restrict__ dE)
{
    const int l = threadIdx.x;
    const int wq = l >> 6;
    const int lane = l & 63;
    const int c = lane & 15, q = lane >> 4;
    const int base = blockIdx.x * ATB;

    __shared__ unsigned short aAh[2][16 * 128], aAl[2][16 * 128];
    __shared__ float fshf[16][52];
    __shared__ float dx1s[16][112];
    __shared__ float bias[4][128];
    __shared__ float eip[2][16];
    __shared__ int aid[16];

    if (l < 16) aid[l] = order[base + l];
    __syncthreads();
    int first = -1;
    #pragma unroll
    for (int a = 0; a < 16; ++a) { int v = aid[a]; if (first < 0 && v >= 0) first = v; }
    if (first < 0) return;
    const int ty = (itype[first] == 8) ? 1 : 0;

    // stage biases + w3 (f32)
    for (int idx = l; idx < 512; idx += 128) {
        int row = idx >> 7, col = idx & 127;
        const float* s = (row == 0) ? B0 : (row == 1) ? B1 : (row == 2) ? B2 : W3;
        bias[row][col] = (col < 100) ? s[ty * 100 + col] : 0.0f;
    }
    // stage feats: f32 copy + split-bf16 into buf0 (swizzled, zero-padded)
    for (int idx = l; idx < 16 * 128; idx += 128) {
        int a = idx >> 7, k = idx & 127;
        float v = (k < 50 && aid[a] >= 0) ? feat[(size_t)aid[a] * 50 + k] : 0.0f;
        unsigned short h = f2bh(v);
        int p = (a << 7) | (k ^ ((a & 7) << 3));
        aAh[0][p] = h; aAl[0][p] = f2bh(v - bh2f(h));
        if (k < 52) fshf[a][k] = v;
    }
    __syncthreads();

    const unsigned short* wt0h = wsu + OFF_WT0H + ty * 8192;
    const unsigned short* wt0l = wsu + OFF_WT0L + ty * 8192;
    const unsigned short* wt1h = wsu + OFF_WT1H + ty * 16384;
    const unsigned short* wt1l = wsu + OFF_WT1L + ty * 16384;
    const unsigned short* wt2h = wsu + OFF_WT2H + ty * 16384;
    const unsigned short* wt2l = wsu + OFF_WT2L + ty * 16384;
    const unsigned short* wm0h = wsu + OFF_WRM0H + ty * 8192;
    const unsigned short* wm0l = wsu + OFF_WRM0L + ty * 8192;
    const unsigned short* wm1h = wsu + OFF_WRM1H + ty * 16384;
    const unsigned short* wm1l = wsu + OFF_WRM1L + ty * 16384;
    const unsigned short* wm2h = wsu + OFF_WRM2H + ty * 16384;
    const unsigned short* wm2l = wsu + OFF_WRM2L + ty * 16384;

    f32x4 acc[4];
    float xr[4][4], h0r[4][4], h1r[4][4], h2r[4][4], dxr[4][4];

    // ---------------- L0 ----------------
    #pragma unroll
    for (int n = 0; n < 4; ++n) acc[n] = (f32x4){0.f, 0.f, 0.f, 0.f};
    GEMM_PASS(0, wt0h, wt0l, 2, 64, wq * 4, 4, acc);
    #pragma unroll
    for (int n = 0; n < 4; ++n) {
        int j = c + 16 * (wq * 4 + n);
        float bj = bias[0][j];
        #pragma unroll
        for (int r = 0; r < 4; ++r) {
            int a = q * 4 + r;
            float z = acc[n][r] + bj;
            float h = 0.0f, x = 0.0f;
            if (j < 100) {
                h = fast_tanh(z);
                x = h + fshf[a][(j < 50) ? j : (j - 50)];
            }
            h0r[n][r] = h;
            xr[n][r] = x;
            unsigned short hh = f2bh(x);
            int p = (a << 7) | (j ^ ((a & 7) << 3));
            aAh[1][p] = hh; aAl[1][p] = f2bh(x - bh2f(hh));
        }
    }
    __syncthreads();

    // ---------------- L1 ----------------
    #pragma unroll
    for (int n = 0; n < 4; ++n) acc[n] = (f32x4){0.f, 0.f, 0.f, 0.f};
    GEMM_PASS(1, wt1h, wt1l, 4, 128, wq * 4, 4, acc);
    #pragma unroll
    for (int n = 0; n < 4; ++n) {
        int j = c + 16 * (wq * 4 + n);
        float bj = bias[1][j];
        #pragma unroll
        for (int r = 0; r < 4; ++r) {
            int a = q * 4 + r;
            float z = acc[n][r] + bj;
            float h = (j < 100) ? fast_tanh(z) : 0.0f;
            float x = (j < 100) ? (h + xr[n][r]) : 0.0f;
            h1r[n][r] = h;
            xr[n][r] = x;
            unsigned short hh = f2bh(x);
            int p = (a << 7) | (j ^ ((a & 7) << 3));
            aAh[0][p] = hh; aAl[0][p] = f2bh(x - bh2f(hh));
        }
    }
    __syncthreads();

    // ---------------- L2 ----------------
    #pragma unroll
    for (int n = 0; n < 4; ++n) acc[n] = (f32x4){0.f, 0.f, 0.f, 0.f};
    GEMM_PASS(0, wt2h, wt2l, 4, 128, wq * 4, 4, acc);
    #pragma unroll
    for (int n = 0; n < 4; ++n) {
        int j = c + 16 * (wq * 4 + n);
        float bj = bias[2][j];
        #pragma unroll
        for (int r = 0; r < 4; ++r) {
            float z = acc[n][r] + bj;
            float h = (j < 100) ? fast_tanh(z) : 0.0f;
            h2r[n][r] = h;
            xr[n][r] = (j < 100) ? (h + xr[n][r]) : 0.0f;   // x3
        }
    }

    // ---- Ei partials + dz2 into buf1 ----
    float p4[4] = {0.f, 0.f, 0.f, 0.f};
    #pragma unroll
    for (int n = 0; n < 4; ++n) {
        int j = c + 16 * (wq * 4 + n);
        float w = bias[3][j];
        #pragma unroll
        for (int r = 0; r < 4; ++r) p4[r] += xr[n][r] * w;
    }
    #pragma unroll
    for (int off = 1; off < 16; off <<= 1) {
        #pragma unroll
        for (int r = 0; r < 4; ++r) p4[r] += __shfl_xor(p4[r], off);
    }
    if (c == 0) {
        #pragma unroll
        for (int r = 0; r < 4; ++r) eip[wq][q * 4 + r] = p4[r];
    }
    #pragma unroll
    for (int n = 0; n < 4; ++n) {
        int j = c + 16 * (wq * 4 + n);
        float w3j = bias[3][j];
        #pragma unroll
        for (int r = 0; r < 4; ++r) {
            int a = q * 4 + r;
            float d = w3j * (1.0f - h2r[n][r] * h2r[n][r]);
            unsigned short hh = f2bh(d);
            int p = (a << 7) | (j ^ ((a & 7) << 3));
            aAh[1][p] = hh; aAl[1][p] = f2bh(d - bh2f(hh));
        }
    }
    __syncthreads();
    if (l < 16) {
        int v = aid[l];
        if (v >= 0) Ei[v] = eip[0][l] + eip[1][l] + B3[ty];
    }

    // ---- bwd2: dx2 = W2·dz2 + w3 ----
    #pragma unroll
    for (int n = 0; n < 4; ++n) acc[n] = (f32x4){0.f, 0.f, 0.f, 0.f};
    GEMM_PASS(1, wm2h, wm2l, 4, 128, wq * 4, 4, acc);
    #pragma unroll
    for (int n = 0; n < 4; ++n) {
        int i = c + 16 * (wq * 4 + n);
        float w3i = bias[3][i];
        #pragma unroll
        for (int r = 0; r < 4; ++r) {
            int a = q * 4 + r;
            dxr[n][r] = acc[n][r] + w3i;
            float d = dxr[n][r] * (1.0f - h1r[n][r] * h1r[n][r]);   // dz1
            unsigned short hh = f2bh(d);
            int p = (a << 7) | (i ^ ((a & 7) << 3));
            aAh[0][p] = hh; aAl[0][p] = f2bh(d - bh2f(hh));
        }
    }
    __syncthreads();

    // ---- bwd1: dx1 = dx2 + W1·dz1 ----
    #pragma unroll
    for (int n = 0; n < 4; ++n) acc[n] = (f32x4){0.f, 0.f, 0.f, 0.f};
    GEMM_PASS(0, wm1h, wm1l, 4, 128, wq * 4, 4, acc);
    #pragma unroll
    for (int n = 0; n < 4; ++n) {
        int i = c + 16 * (wq * 4 + n);
        #pragma unroll
        for (int r = 0; r < 4; ++r) {
            int a = q * 4 + r;
            dxr[n][r] += acc[n][r];
            if (i < 112) dx1s[a][i] = dxr[n][r];
            float d = dxr[n][r] * (1.0f - h0r[n][r] * h0r[n][r]);   // dz0
            unsigned short hh = f2bh(d);
            int p = (a << 7) | (i ^ ((a & 7) << 3));
            aAh[1][p] = hh; aAl[1][p] = f2bh(d - bh2f(hh));
        }
    }
    __syncthreads();

    // ---- bwd0: dE = dx1[f] + dx1[f+50] + W0·dz0 ----
    f32x4 acc2[2];
    #pragma unroll
    for (int s = 0; s < 2; ++s) acc2[s] = (f32x4){0.f, 0.f, 0.f, 0.f};
    GEMM_PASS(1, wm0h, wm0l, 4, 128, wq * 2, 2, acc2);
    #pragma unroll
    for (int s = 0; s < 2; ++s) {
        int f = c + 16 * (wq * 2 + s);
        if (f < 50) {
            #pragma unroll
            for (int r = 0; r < 4; ++r) {
                int a = q * 4 + r;
                float g = acc2[s][r] + dx1s[a][f] + dx1s[a][f + 50];
                int v = aid[a];
                if (v >= 0) dE[(size_t)v * FEAT + f] = g;
            }
        }
    }
}

// --------------------------------------------------------------- force ----
__global__ __launch_bounds__(FTHREADS) void force_kernel(
    const int* __restrict__ itype, const int* __restrict__ nlist,
    const float* __restrict__ dR, const float* __restrict__ dE,
    float* __restrict__ partial)
{
    const int blk = blockIdx.x;
    const int b = blk / GPB;
    const int g = blk - b * GPB;
    const int t = threadIdx.x;

    __shared__ float acc[(Nn + 1) * 3];
    __shared__ float desh[CPG][FEAT];

    for (int idx = t; idx < (Nn + 1) * 3; idx += FTHREADS) acc[idx] = 0.0f;
    for (int idx = t; idx < CPG * FEAT; idx += FTHREADS)
        ((float*)desh)[idx] = dE[((size_t)(b * Nn) + g * CPG) * FEAT + idx];
    __syncthreads();

    for (int p = t; p < CPG * Mn; p += FTHREADS) {
        int cc = p / Mn, m = p - cc * Mn;
        int n = g * CPG + cc;
        size_t pair = (size_t)(b * Nn + n) * Mn + m;
        float4 qv = ((const float4*)dR)[pair];
        int v = nlist[pair];
        if (v > 0) {
            float r = qv.x;
            if (r < RMAXc && r > 0.0f) {
                int tt = (itype[b * Nn + v - 1] == 8) ? 1 : 0;
                float cw  = 0.5f * __cosf(PIc * r) + 0.5f;
                float dcw = -0.5f * PIc * __sinf(PIc * r);
                float s = 0.0f;
                const float* de = &desh[cc][tt * NB];
                #pragma unroll
                for (int k = 0; k < NB; ++k) {
                    float d = r - (0.5f + k * RSTEP);
                    float e = __expf(-d * d);
                    s += de[k] * (e * dcw - 2.0f * d * e * cw);
                }
                float inv = 1.0f / r;
                float fx = s * qv.y * inv, fy = s * qv.z * inv, fz = s * qv.w * inv;
                atomicAdd(&acc[v * 3 + 0], fx);
                atomicAdd(&acc[v * 3 + 1], fy);
                atomicAdd(&acc[v * 3 + 2], fz);
                atomicAdd(&acc[(n + 1) * 3 + 0], -fx);
                atomicAdd(&acc[(n + 1) * 3 + 1], -fy);
                atomicAdd(&acc[(n + 1) * 3 + 2], -fz);
            }
        }
    }
    __syncthreads();

    float* pout = partial + (size_t)blk * ((Nn + 1) * 3);
    for (int idx = t; idx < (Nn + 1) * 3; idx += FTHREADS) pout[idx] = acc[idx];
}

// ----------------------------------------------------- freduce (+etot) ----
__global__ __launch_bounds__(256) void freduce_kernel(
    const float* __restrict__ partial, const float* __restrict__ Ei,
    float* __restrict__ Force, float* __restrict__ Etot)
{
    if (blockIdx.x == 48) {   // etot
        const int t = threadIdx.x;
        __shared__ float red[256];
        for (int b = 0; b < Bn; ++b) {
            float s = 0.0f;
            for (int i = t; i < Nn; i += 256) s += Ei[b * Nn + i];
            red[t] = s;
            __syncthreads();
            for (int st = 128; st > 0; st >>= 1) {
                if (t < st) red[t] += red[t + st];
                __syncthreads();
            }
            if (t == 0) Etot[b] = red[0];
            __syncthreads();
        }
        return;
    }
    int idx = blockIdx.x * 256 + threadIdx.x;
    if (idx >= Bn * Nn * 3) return;
    int b = idx / (Nn * 3);
    int r = idx - b * (Nn * 3);
    int i = r / 3, ch = r - i * 3;
    float s = 0.0f;
    for (int g = 0; g < GPB; ++g)
        s += partial[((size_t)(b * GPB + g)) * ((Nn + 1) * 3) + (size_t)(i + 1) * 3 + ch];
    Force[idx] = s;
}

// -------------------------------------------------------------- launch ----
extern "C" void kernel_launch(void* const* d_in, const int* in_sizes, int n_in,
                              void* d_out, int out_size, void* d_ws, size_t ws_size,
                              hipStream_t stream)
{
    const int*   itype = (const int*)d_in[0];
    const int*   nlist = (const int*)d_in[1];
    const float* dR    = (const float*)d_in[2];
    const float* W0 = (const float*)d_in[3];  const float* B0 = (const float*)d_in[4];
    const float* W1 = (const float*)d_in[5];  const float* B1 = (const float*)d_in[6];
    const float* W2 = (const float*)d_in[7];  const float* B2 = (const float*)d_in[8];
    const float* W3 = (const float*)d_in[9];  const float* B3 = (const float*)d_in[10];

    float* out   = (float*)d_out;
    float* Etot  = out;                    // [B,1]
    float* Ei    = out + Bn;               // [B,N,1]
    float* Force = out + Bn + Bn * Nn;     // [B,N,3]

    float* feat    = (float*)d_ws;                              // 204800 f32
    float* dEp     = feat + (size_t)NATOMS * FEAT;              // 204800 f32
    float* partial = dEp + (size_t)NATOMS * FEAT;               // 393600 f32
    int*   order   = (int*)(partial + (size_t)Bn * GPB * (Nn + 1) * 3);  // 4112 int
    unsigned short* wsu = (unsigned short*)(order + ORDER_LEN); // 327680 ushort

    prep_kernel   <<<641, 256, 0, stream>>>(itype, W0, W1, W2, order, wsu);
    feat_kernel   <<<NATOMS, 128, 0, stream>>>(itype, nlist, dR, feat);
    mlp_kernel    <<<MLP_BLOCKS, 128, 0, stream>>>(feat, itype, order, wsu,
                                                   B0, B1, B2, W3, B3, Ei, dEp);
    force_kernel  <<<Bn * GPB, FTHREADS, 0, stream>>>(itype, nlist, dR, dEp, partial);
    freduce_kernel<<<49, 256, 0, stream>>>(partial, Ei, Force, Etot);
}